// Round 8
// baseline (462.868 us; speedup 1.0000x reference)
//
#include <hip/hip_runtime.h>

#define DIM 128
#define TSTR 132   // LDS fp32 tile row stride (floats): balanced banks for b128 reads

typedef unsigned int uint32;
typedef short bf16x8 __attribute__((ext_vector_type(8)));
typedef float f32x4 __attribute__((ext_vector_type(4)));

__device__ __forceinline__ unsigned short f2b(float f) {
    return (unsigned short)((__float_as_uint(f) + 0x8000u) >> 16);
}
__device__ __forceinline__ uint32 packbf2(float lo, float hi) {
    uint32 a = __float_as_uint(lo);
    uint32 b = __float_as_uint(hi);
    return ((a + 0x8000u) >> 16) | ((b + 0x8000u) & 0xffff0000u);
}
__device__ __forceinline__ float bflo(uint32 u) { return __uint_as_float(u << 16); }
__device__ __forceinline__ float bfhi(uint32 u) { return __uint_as_float(u & 0xffff0000u); }

// ---------------- degree count ----------------
__global__ __launch_bounds__(256) void k_count(const int* __restrict__ dst,
                                               int* __restrict__ cnt, int E) {
    int e = blockIdx.x * 256 + threadIdx.x;
    if (e < E) atomicAdd(&cnt[dst[e]], 1);
}

// g0 = dinv ⊙ x, bf16-packed
__global__ __launch_bounds__(256) void k_scaleg(const float* __restrict__ x,
                                                const float* __restrict__ dinv,
                                                uint32* __restrict__ g, int n) {
    int t = blockIdx.x * 256 + threadIdx.x;
    if (t >= n * 64) return;
    int node = t >> 6;
    float dv = dinv[node];
    float2 v = ((const float2*)x)[t];
    g[t] = packbf2(dv * v.x, dv * v.y);
}

// ---------------- scan (+dinv fused) ----------------
__global__ __launch_bounds__(256) void k_scan1(const int* __restrict__ cnt,
                                               int* __restrict__ incl,
                                               int* __restrict__ bsums,
                                               float* __restrict__ dinv, int n) {
    __shared__ int tmp[256];
    int i = blockIdx.x * 256 + threadIdx.x;
    int t = threadIdx.x;
    int c = (i < n) ? cnt[i] : 0;
    if (i < n) dinv[i] = rsqrtf((float)(c + 1));
    tmp[t] = c;
    __syncthreads();
#pragma unroll
    for (int off = 1; off < 256; off <<= 1) {
        int v = (t >= off) ? tmp[t - off] : 0;
        __syncthreads();
        tmp[t] += v;
        __syncthreads();
    }
    if (i < n) incl[i] = tmp[t];
    if (t == 255) bsums[blockIdx.x] = tmp[255];
}

__global__ __launch_bounds__(512) void k_scan2(int* __restrict__ bsums, int nb) {
    __shared__ int tmp[512];
    int t = threadIdx.x;
    tmp[t] = (t < nb) ? bsums[t] : 0;
    __syncthreads();
#pragma unroll
    for (int off = 1; off < 512; off <<= 1) {
        int v = (t >= off) ? tmp[t - off] : 0;
        __syncthreads();
        tmp[t] += v;
        __syncthreads();
    }
    if (t < nb) bsums[t] = (t == 0) ? 0 : tmp[t - 1];
}

__global__ __launch_bounds__(256) void k_scan3(int* __restrict__ incl,
                                               const int* __restrict__ bsums, int n) {
    int i = blockIdx.x * 256 + threadIdx.x;
    if (i < n) incl[i] += bsums[blockIdx.x];
}

// ---------------- CSR fill ----------------
__global__ __launch_bounds__(256) void k_fill(const int* __restrict__ src,
                                              const int* __restrict__ dst,
                                              int* __restrict__ incl,
                                              int* __restrict__ srcs, int E) {
    int e = blockIdx.x * 256 + threadIdx.x;
    if (e >= E) return;
    int p = atomicSub(&incl[dst[e]], 1) - 1;
    srcs[p] = src[e];
}

// ---------------- W -> per-lane bf16 B-fragments ----------------
// frag f = (w*2 + cs)*4 + ks ; element j, lane l:
//   n = w*32 + cs*16 + (l&15),  k = ks*32 + (l>>4)*8 + j
__global__ __launch_bounds__(256) void k_prepW(const float* __restrict__ Ws,
                                               short* __restrict__ Wb, int total) {
    int t = blockIdx.x * 256 + threadIdx.x;
    if (t >= total) return;
    int layer = t >> 14;
    int idx = t & 16383;
    int j = idx & 7;
    int l = (idx >> 3) & 63;
    int f = idx >> 9;
    int ks = f & 3;
    int cs = (f >> 2) & 1;
    int w = f >> 3;
    int nn = w * 32 + cs * 16 + (l & 15);
    int kk = ks * 32 + (l >> 4) * 8 + j;
    Wb[t] = (short)f2b(Ws[(size_t)layer * DIM * DIM + kk * DIM + nn]);
}

// ---------------- fused layer v2 ----------------
// phase 0: stage rowptr slice + self rows (fp32) into LDS tile [32][TSTR].
// phase 1: block's edge range split into 4 contiguous slices, one per wave.
//          Wave streams edges (x4 unrolled gathers, lane = 2 cols), accumulates
//          while dst unchanged, flushes to LDS via ds_add_f32 at boundaries.
// phase 2: read tile fp32, scale by dinv, convert bf16, MFMA -> g_next | out.
__global__ __launch_bounds__(256) void k_layer(const uint32* __restrict__ g,
                                               const int* __restrict__ srcs,
                                               const int* __restrict__ rowptr,
                                               const float* __restrict__ dinv,
                                               const short* __restrict__ Wb,
                                               const float* __restrict__ bias,
                                               uint32* __restrict__ Gn,
                                               float* __restrict__ Out,
                                               int n, int E, int final_layer) {
    __shared__ __align__(16) float tile[32 * TSTR];   // 16.9 KB fp32 accumulators
    __shared__ int rowS[33];
    int tid = threadIdx.x;
    int w = tid >> 6;       // wave 0..3
    int lane = tid & 63;
    int row0 = blockIdx.x * 32;

    // preload B-fragments (latency hides under phase 0/1)
    const bf16x8* wb = (const bf16x8*)Wb;
    bf16x8 bfrag[2][4];
#pragma unroll
    for (int cs = 0; cs < 2; ++cs)
#pragma unroll
        for (int ks = 0; ks < 4; ++ks)
            bfrag[cs][ks] = wb[((w * 2 + cs) * 4 + ks) * 64 + lane];

    // ---- phase 0: rowptr slice + self rows ----
    if (tid < 33) {
        int r = row0 + tid;
        rowS[tid] = (r < n) ? rowptr[r] : E;
    }
#pragma unroll
    for (int i = 0; i < 8; ++i) {
        int rl = w * 8 + i;
        int node = row0 + rl;
        uint32 u = (node < n) ? g[(size_t)node * 64 + lane] : 0u;
        *(float2*)(tile + rl * TSTR + 2 * lane) = make_float2(bflo(u), bfhi(u));
    }
    __syncthreads();

    // ---- phase 1: balanced cooperative edge gather ----
    {
        int rs = rowS[0], re = rowS[32];
        int sz = (re - rs + 3) >> 2;
        int p0 = rs + w * sz;
        int p1 = min(p0 + sz, re);
        if (p0 < p1) {
            int j = 0;
            while (rowS[j + 1] <= p0) ++j;
            int bnd = rowS[j + 1];
            float a0 = 0.f, a1 = 0.f;
            int p = p0;

#define STEP(T, VV)                                                    \
            {                                                          \
                if (p + (T) >= bnd) {                                  \
                    atomicAdd(&tile[j * TSTR + 2 * lane], a0);         \
                    atomicAdd(&tile[j * TSTR + 2 * lane + 1], a1);     \
                    a0 = 0.f; a1 = 0.f;                                \
                    do { ++j; bnd = rowS[j + 1]; } while (p + (T) >= bnd); \
                }                                                      \
                a0 += bflo(VV); a1 += bfhi(VV);                        \
            }

            for (; p + 4 <= p1; p += 4) {
                int s0 = srcs[p + 0];
                int s1 = srcs[p + 1];
                int s2 = srcs[p + 2];
                int s3 = srcs[p + 3];
                uint32 v0 = g[(size_t)s0 * 64 + lane];
                uint32 v1 = g[(size_t)s1 * 64 + lane];
                uint32 v2 = g[(size_t)s2 * 64 + lane];
                uint32 v3 = g[(size_t)s3 * 64 + lane];
                STEP(0, v0) STEP(1, v1) STEP(2, v2) STEP(3, v3)
            }
            for (; p < p1; ++p) {
                uint32 v = g[(size_t)srcs[p] * 64 + lane];
                STEP(0, v)
            }
#undef STEP
            atomicAdd(&tile[j * TSTR + 2 * lane], a0);
            atomicAdd(&tile[j * TSTR + 2 * lane + 1], a1);
        }
    }
    __syncthreads();

    // ---- phase 2: scale + convert + MFMA ----
    int lr = lane & 15;
    int lg = lane >> 4;
    int n0 = row0 + lr;
    int n1 = row0 + 16 + lr;
    float dA = (n0 < n) ? dinv[n0] : 0.f;
    float dB = (n1 < n) ? dinv[n1] : 0.f;

    f32x4 acc[2][2];
#pragma unroll
    for (int rs = 0; rs < 2; ++rs)
#pragma unroll
        for (int cs = 0; cs < 2; ++cs) acc[rs][cs] = (f32x4){0.f, 0.f, 0.f, 0.f};

#pragma unroll
    for (int ks = 0; ks < 4; ++ks) {
        const float* t0 = tile + lr * TSTR + ks * 32 + lg * 8;
        const float* t1 = tile + (16 + lr) * TSTR + ks * 32 + lg * 8;
        float4 xa = *(const float4*)t0;
        float4 xb = *(const float4*)(t0 + 4);
        float4 ya = *(const float4*)t1;
        float4 yb = *(const float4*)(t1 + 4);
        bf16x8 a0, a1;
        a0[0] = (short)f2b(dA * xa.x); a0[1] = (short)f2b(dA * xa.y);
        a0[2] = (short)f2b(dA * xa.z); a0[3] = (short)f2b(dA * xa.w);
        a0[4] = (short)f2b(dA * xb.x); a0[5] = (short)f2b(dA * xb.y);
        a0[6] = (short)f2b(dA * xb.z); a0[7] = (short)f2b(dA * xb.w);
        a1[0] = (short)f2b(dB * ya.x); a1[1] = (short)f2b(dB * ya.y);
        a1[2] = (short)f2b(dB * ya.z); a1[3] = (short)f2b(dB * ya.w);
        a1[4] = (short)f2b(dB * yb.x); a1[5] = (short)f2b(dB * yb.y);
        a1[6] = (short)f2b(dB * yb.z); a1[7] = (short)f2b(dB * yb.w);
#pragma unroll
        for (int cs = 0; cs < 2; ++cs) {
            acc[0][cs] = __builtin_amdgcn_mfma_f32_16x16x32_bf16(a0, bfrag[cs][ks], acc[0][cs], 0, 0, 0);
            acc[1][cs] = __builtin_amdgcn_mfma_f32_16x16x32_bf16(a1, bfrag[cs][ks], acc[1][cs], 0, 0, 0);
        }
    }

    float b0 = bias[w * 32 + lr];
    float b1 = bias[w * 32 + 16 + lr];

    // C/D layout (m89-verified): col = l&15, row = (l>>4)*4 + reg
#pragma unroll
    for (int rs = 0; rs < 2; ++rs)
#pragma unroll
        for (int r = 0; r < 4; ++r) {
            int grow = row0 + rs * 16 + lg * 4 + r;
            if (grow < n) {
                float h0 = fmaxf(acc[rs][0][r] + b0, 0.f);
                float h1 = fmaxf(acc[rs][1][r] + b1, 0.f);
                if (final_layer) {
                    Out[(size_t)grow * DIM + w * 32 + lr]      = h0;
                    Out[(size_t)grow * DIM + w * 32 + 16 + lr] = h1;
                } else {
                    float dv = dinv[grow];
                    unsigned short* gp = (unsigned short*)Gn;
                    gp[(size_t)grow * DIM + w * 32 + lr]      = f2b(dv * h0);
                    gp[(size_t)grow * DIM + w * 32 + 16 + lr] = f2b(dv * h1);
                }
            }
        }
}

extern "C" void kernel_launch(void* const* d_in, const int* in_sizes, int n_in,
                              void* d_out, int out_size, void* d_ws, size_t ws_size,
                              hipStream_t stream) {
    const float* x  = (const float*)d_in[0];
    const int*   ei = (const int*)d_in[1];
    const float* Ws = (const float*)d_in[2];
    const float* bs = (const float*)d_in[3];

    const int N = in_sizes[0] / DIM;           // 100000
    const int E = in_sizes[1] / 2;             // 640000
    const int L = in_sizes[2] / (DIM * DIM);   // 3

    const int* src = ei;
    const int* dst = ei + E;

    float* out = (float*)d_out;

    char* ws = (char*)d_ws;
    uint32* g0   = (uint32*)ws;                ws += (size_t)N * 64 * 4;   // 25.6 MB
    uint32* g1   = (uint32*)ws;                ws += (size_t)N * 64 * 4;   // 25.6 MB
    short* Wb    = (short*)ws;                 ws += (size_t)L * 16384 * 2;
    float* dinv  = (float*)ws;                 ws += (size_t)N * 4;
    int*   cnt   = (int*)ws;                   ws += (size_t)N * 4;
    int*   incl  = (int*)ws;                   ws += (size_t)N * 4;
    int*   srcs  = (int*)ws;                   ws += (size_t)E * 4;
    int*   bsums = (int*)ws;                   ws += 512 * 4;

    const int nbN = (N + 255) / 256;           // 391 (< 512)
    const int nbE = (E + 255) / 256;
    const int totW = L * 16384;

    // ---- prepass ----
    k_prepW<<<(totW + 255) / 256, 256, 0, stream>>>(Ws, Wb, totW);
    hipMemsetAsync(cnt, 0, (size_t)N * 4, stream);
    k_count<<<nbE, 256, 0, stream>>>(dst, cnt, E);
    k_scan1<<<nbN, 256, 0, stream>>>(cnt, incl, bsums, dinv, N);
    k_scan2<<<1, 512, 0, stream>>>(bsums, nbN);
    k_scaleg<<<(N * 64 + 255) / 256, 256, 0, stream>>>(x, dinv, g0, N);
    k_scan3<<<nbN, 256, 0, stream>>>(incl, bsums, N);
    k_fill <<<nbE, 256, 0, stream>>>(src, dst, incl, srcs, E);

    // ---- fused layers ----
    const int nblk = (N + 31) / 32;
    uint32* gin = g0;
    for (int l = 0; l < L; ++l) {
        uint32* gout = (gin == g0) ? g1 : g0;
        k_layer<<<nblk, 256, 0, stream>>>(gin, srcs, incl, dinv,
                                          Wb + (size_t)l * 16384,
                                          bs + (size_t)l * DIM,
                                          gout, out, N, E, l == L - 1);
        gin = gout;
    }
}

// Round 9
// 309.414 us; speedup vs baseline: 1.4960x; 1.4960x over previous
//
#include <hip/hip_runtime.h>

#define DIM 128
#define MROW 272   // LDS bf16 m-tile row stride in bytes (16B-aligned, 2-way banks max)

typedef unsigned int uint32;
typedef short bf16x8 __attribute__((ext_vector_type(8)));
typedef float f32x4 __attribute__((ext_vector_type(4)));

__device__ __forceinline__ unsigned short f2b(float f) {
    return (unsigned short)((__float_as_uint(f) + 0x8000u) >> 16);
}
__device__ __forceinline__ uint32 packbf2(float lo, float hi) {
    uint32 a = __float_as_uint(lo);
    uint32 b = __float_as_uint(hi);
    return ((a + 0x8000u) >> 16) | ((b + 0x8000u) & 0xffff0000u);
}
__device__ __forceinline__ float bflo(uint32 u) { return __uint_as_float(u << 16); }
__device__ __forceinline__ float bfhi(uint32 u) { return __uint_as_float(u & 0xffff0000u); }

// ---------------- degree count ----------------
__global__ __launch_bounds__(256) void k_count(const int* __restrict__ dst,
                                               int* __restrict__ cnt, int E) {
    int e = blockIdx.x * 256 + threadIdx.x;
    if (e < E) atomicAdd(&cnt[dst[e]], 1);
}

// g0 = dinv ⊙ x, bf16-packed
__global__ __launch_bounds__(256) void k_scaleg(const float* __restrict__ x,
                                                const float* __restrict__ dinv,
                                                uint32* __restrict__ g, int n) {
    int t = blockIdx.x * 256 + threadIdx.x;
    if (t >= n * 64) return;
    int node = t >> 6;
    float dv = dinv[node];
    float2 v = ((const float2*)x)[t];
    g[t] = packbf2(dv * v.x, dv * v.y);
}

// ---------------- scan (+dinv fused) ----------------
__global__ __launch_bounds__(256) void k_scan1(const int* __restrict__ cnt,
                                               int* __restrict__ incl,
                                               int* __restrict__ bsums,
                                               float* __restrict__ dinv, int n) {
    __shared__ int tmp[256];
    int i = blockIdx.x * 256 + threadIdx.x;
    int t = threadIdx.x;
    int c = (i < n) ? cnt[i] : 0;
    if (i < n) dinv[i] = rsqrtf((float)(c + 1));
    tmp[t] = c;
    __syncthreads();
#pragma unroll
    for (int off = 1; off < 256; off <<= 1) {
        int v = (t >= off) ? tmp[t - off] : 0;
        __syncthreads();
        tmp[t] += v;
        __syncthreads();
    }
    if (i < n) incl[i] = tmp[t];
    if (t == 255) bsums[blockIdx.x] = tmp[255];
}

__global__ __launch_bounds__(512) void k_scan2(int* __restrict__ bsums, int nb) {
    __shared__ int tmp[512];
    int t = threadIdx.x;
    tmp[t] = (t < nb) ? bsums[t] : 0;
    __syncthreads();
#pragma unroll
    for (int off = 1; off < 512; off <<= 1) {
        int v = (t >= off) ? tmp[t - off] : 0;
        __syncthreads();
        tmp[t] += v;
        __syncthreads();
    }
    if (t < nb) bsums[t] = (t == 0) ? 0 : tmp[t - 1];
}

__global__ __launch_bounds__(256) void k_scan3(int* __restrict__ incl,
                                               const int* __restrict__ bsums, int n) {
    int i = blockIdx.x * 256 + threadIdx.x;
    if (i < n) incl[i] += bsums[blockIdx.x];
}

// ---------------- CSR fill ----------------
__global__ __launch_bounds__(256) void k_fill(const int* __restrict__ src,
                                              const int* __restrict__ dst,
                                              int* __restrict__ incl,
                                              int* __restrict__ srcs, int E) {
    int e = blockIdx.x * 256 + threadIdx.x;
    if (e >= E) return;
    int p = atomicSub(&incl[dst[e]], 1) - 1;
    srcs[p] = src[e];
}

// ---------------- W -> per-lane bf16 B-fragments ----------------
// frag f = (w*2 + cs)*4 + ks ; element j, lane l:
//   n = w*32 + cs*16 + (l&15),  k = ks*32 + (l>>4)*8 + j
__global__ __launch_bounds__(256) void k_prepW(const float* __restrict__ Ws,
                                               short* __restrict__ Wb, int total) {
    int t = blockIdx.x * 256 + threadIdx.x;
    if (t >= total) return;
    int layer = t >> 14;
    int idx = t & 16383;
    int j = idx & 7;
    int l = (idx >> 3) & 63;
    int f = idx >> 9;
    int ks = f & 3;
    int cs = (f >> 2) & 1;
    int w = f >> 3;
    int nn = w * 32 + cs * 16 + (l & 15);
    int kk = ks * 32 + (l >> 4) * 8 + j;
    Wb[t] = (short)f2b(Ws[(size_t)layer * DIM * DIM + kk * DIM + nn]);
}

// ---------------- fused layer v3 ----------------
// phase 1: 8 half-wave engines, each owns 4 nodes processed as 2 interleaved pairs.
//          Masked batch-4 gathers (no serial remainder); register accumulate;
//          single non-atomic bf16 tile write per row.
// phase 2: B-fragments from global (pinned after phase 1), A from LDS tile, MFMA.
__global__ __launch_bounds__(256) void k_layer(const uint32* __restrict__ g,
                                               const int* __restrict__ srcs,
                                               const int* __restrict__ rowptr,
                                               const float* __restrict__ dinv,
                                               const short* __restrict__ Wb,
                                               const float* __restrict__ bias,
                                               uint32* __restrict__ Gn,
                                               float* __restrict__ Out,
                                               int n, int E, int final_layer) {
    __shared__ __align__(16) char smem[32 * MROW];   // 8.7 KB bf16 tile
    __shared__ int rowS[33];
    int tid = threadIdx.x;
    int w = tid >> 6;
    int lane = tid & 63;
    int row0 = blockIdx.x * 32;

    if (tid < 33) {
        int r = row0 + tid;
        rowS[tid] = (r < n) ? rowptr[r] : E;
    }
    __syncthreads();

    // ---- phase 1: gather (8 engines x 2 interleaved node-pairs) ----
    {
        int hw = tid >> 5;
        int sub = tid & 31;
        const uint2* g2 = (const uint2*)g;
#pragma unroll
        for (int i = 0; i < 2; ++i) {
            int nlA = hw * 4 + 2 * i;
            int nlB = nlA + 1;
            int nodeA = row0 + nlA;
            int nodeB = row0 + nlB;
            int pA = rowS[nlA], qA = rowS[nlA + 1];
            int pB = rowS[nlB], qB = rowS[nlB + 1];
            float dA = (nodeA < n) ? dinv[nodeA] : 0.f;
            float dB = (nodeB < n) ? dinv[nodeB] : 0.f;
            uint2 z = make_uint2(0u, 0u);
            uint2 uA = (nodeA < n) ? g2[(size_t)nodeA * 32 + sub] : z;
            uint2 uB = (nodeB < n) ? g2[(size_t)nodeB * 32 + sub] : z;
            float aA0 = bflo(uA.x), aA1 = bfhi(uA.x), aA2 = bflo(uA.y), aA3 = bfhi(uA.y);
            float aB0 = bflo(uB.x), aB1 = bfhi(uB.x), aB2 = bflo(uB.y), aB3 = bfhi(uB.y);
            int nb = max(qA - pA, qB - pB);
            for (int t = 0; t < nb; t += 4) {
                int sA[4], sB[4];
                float mA[4], mB[4];
#pragma unroll
                for (int u = 0; u < 4; ++u) {
                    int eA = pA + t + u;
                    int eB = pB + t + u;
                    mA[u] = (eA < qA) ? 1.f : 0.f;
                    mB[u] = (eB < qB) ? 1.f : 0.f;
                    int iA = max(min(eA, qA - 1), pA);
                    int iB = max(min(eB, qB - 1), pB);
                    sA[u] = srcs[iA];
                    sB[u] = srcs[iB];
                }
                uint2 vA[4], vB[4];
#pragma unroll
                for (int u = 0; u < 4; ++u) {
                    vA[u] = g2[(size_t)sA[u] * 32 + sub];
                    vB[u] = g2[(size_t)sB[u] * 32 + sub];
                }
#pragma unroll
                for (int u = 0; u < 4; ++u) {
                    aA0 = fmaf(mA[u], bflo(vA[u].x), aA0);
                    aA1 = fmaf(mA[u], bfhi(vA[u].x), aA1);
                    aA2 = fmaf(mA[u], bflo(vA[u].y), aA2);
                    aA3 = fmaf(mA[u], bfhi(vA[u].y), aA3);
                    aB0 = fmaf(mB[u], bflo(vB[u].x), aB0);
                    aB1 = fmaf(mB[u], bfhi(vB[u].x), aB1);
                    aB2 = fmaf(mB[u], bflo(vB[u].y), aB2);
                    aB3 = fmaf(mB[u], bfhi(vB[u].y), aB3);
                }
            }
            uint2 oA, oB;
            oA.x = packbf2(dA * aA0, dA * aA1);
            oA.y = packbf2(dA * aA2, dA * aA3);
            oB.x = packbf2(dB * aB0, dB * aB1);
            oB.y = packbf2(dB * aB2, dB * aB3);
            *(uint2*)(smem + nlA * MROW + sub * 8) = oA;
            *(uint2*)(smem + nlB * MROW + sub * 8) = oB;
        }
    }
    __syncthreads();
    __builtin_amdgcn_sched_barrier(0);   // keep B-frag loads out of phase 1 (VGPR cap)

    // ---- phase 2: B-fragments + MFMA ----
    const bf16x8* wb = (const bf16x8*)Wb;
    bf16x8 bfrag[2][4];
#pragma unroll
    for (int cs = 0; cs < 2; ++cs)
#pragma unroll
        for (int ks = 0; ks < 4; ++ks)
            bfrag[cs][ks] = wb[((w * 2 + cs) * 4 + ks) * 64 + lane];

    int lr = lane & 15;
    int lg = lane >> 4;

    f32x4 acc[2][2];
#pragma unroll
    for (int rs = 0; rs < 2; ++rs)
#pragma unroll
        for (int cs = 0; cs < 2; ++cs) acc[rs][cs] = (f32x4){0.f, 0.f, 0.f, 0.f};

    const char* base0 = smem + lr * MROW + lg * 16;
    const char* base1 = smem + (16 + lr) * MROW + lg * 16;
#pragma unroll
    for (int ks = 0; ks < 4; ++ks) {
        bf16x8 a0 = *(const bf16x8*)(base0 + ks * 64);
        bf16x8 a1 = *(const bf16x8*)(base1 + ks * 64);
#pragma unroll
        for (int cs = 0; cs < 2; ++cs) {
            acc[0][cs] = __builtin_amdgcn_mfma_f32_16x16x32_bf16(a0, bfrag[cs][ks], acc[0][cs], 0, 0, 0);
            acc[1][cs] = __builtin_amdgcn_mfma_f32_16x16x32_bf16(a1, bfrag[cs][ks], acc[1][cs], 0, 0, 0);
        }
    }

    float b0 = bias[w * 32 + lr];
    float b1 = bias[w * 32 + 16 + lr];

    // C/D layout (m89-verified): col = l&15, row = (l>>4)*4 + reg
#pragma unroll
    for (int rs = 0; rs < 2; ++rs)
#pragma unroll
        for (int r = 0; r < 4; ++r) {
            int grow = row0 + rs * 16 + lg * 4 + r;
            if (grow < n) {
                float h0 = fmaxf(acc[rs][0][r] + b0, 0.f);
                float h1 = fmaxf(acc[rs][1][r] + b1, 0.f);
                if (final_layer) {
                    Out[(size_t)grow * DIM + w * 32 + lr]      = h0;
                    Out[(size_t)grow * DIM + w * 32 + 16 + lr] = h1;
                } else {
                    float dv = dinv[grow];
                    unsigned short* gp = (unsigned short*)Gn;
                    gp[(size_t)grow * DIM + w * 32 + lr]      = f2b(dv * h0);
                    gp[(size_t)grow * DIM + w * 32 + 16 + lr] = f2b(dv * h1);
                }
            }
        }
}

extern "C" void kernel_launch(void* const* d_in, const int* in_sizes, int n_in,
                              void* d_out, int out_size, void* d_ws, size_t ws_size,
                              hipStream_t stream) {
    const float* x  = (const float*)d_in[0];
    const int*   ei = (const int*)d_in[1];
    const float* Ws = (const float*)d_in[2];
    const float* bs = (const float*)d_in[3];

    const int N = in_sizes[0] / DIM;           // 100000
    const int E = in_sizes[1] / 2;             // 640000
    const int L = in_sizes[2] / (DIM * DIM);   // 3

    const int* src = ei;
    const int* dst = ei + E;

    float* out = (float*)d_out;

    char* ws = (char*)d_ws;
    uint32* g0   = (uint32*)ws;                ws += (size_t)N * 64 * 4;   // 25.6 MB
    uint32* g1   = (uint32*)ws;                ws += (size_t)N * 64 * 4;   // 25.6 MB
    short* Wb    = (short*)ws;                 ws += (size_t)L * 16384 * 2;
    float* dinv  = (float*)ws;                 ws += (size_t)N * 4;
    int*   cnt   = (int*)ws;                   ws += (size_t)N * 4;
    int*   incl  = (int*)ws;                   ws += (size_t)N * 4;
    int*   srcs  = (int*)ws;                   ws += (size_t)E * 4;
    int*   bsums = (int*)ws;                   ws += 512 * 4;

    const int nbN = (N + 255) / 256;           // 391 (< 512)
    const int nbE = (E + 255) / 256;
    const int totW = L * 16384;

    // ---- prepass ----
    k_prepW<<<(totW + 255) / 256, 256, 0, stream>>>(Ws, Wb, totW);
    hipMemsetAsync(cnt, 0, (size_t)N * 4, stream);
    k_count<<<nbE, 256, 0, stream>>>(dst, cnt, E);
    k_scan1<<<nbN, 256, 0, stream>>>(cnt, incl, bsums, dinv, N);
    k_scan2<<<1, 512, 0, stream>>>(bsums, nbN);
    k_scaleg<<<(N * 64 + 255) / 256, 256, 0, stream>>>(x, dinv, g0, N);
    k_scan3<<<nbN, 256, 0, stream>>>(incl, bsums, N);
    k_fill <<<nbE, 256, 0, stream>>>(src, dst, incl, srcs, E);

    // ---- fused layers ----
    const int nblk = (N + 31) / 32;
    uint32* gin = g0;
    for (int l = 0; l < L; ++l) {
        uint32* gout = (gin == g0) ? g1 : g0;
        k_layer<<<nblk, 256, 0, stream>>>(gin, srcs, incl, dinv,
                                          Wb + (size_t)l * 16384,
                                          bs + (size_t)l * DIM,
                                          gout, out, N, E, l == L - 1);
        gin = gout;
    }
}